// Round 15
// baseline (354.164 us; speedup 1.0000x reference)
//
#include <hip/hip_runtime.h>
#include <cstdint>

#define NN 2048
#define DD 128
#define BATCH 8
#define NROWS 16384
#define MARGIN 0.02f     // >= 2.5x the rigorous 2E bound (E<0.004: bf16 2^-8 + fp32-acc)
#define CAP 64

typedef __attribute__((ext_vector_type(8))) short bf16x8;
typedef __attribute__((ext_vector_type(4))) float f32x4;
typedef unsigned long long u64;
typedef unsigned int u32;

// ---------------- K1: norms + bf16 normalized copy (validated R14) ----------------
__global__ __launch_bounds__(256) void k_normalize(const float* __restrict__ x,
                                                   double* __restrict__ rinv,
                                                   u32* __restrict__ nb) {
  const int wave = threadIdx.x >> 6, lane = threadIdx.x & 63;
  const long long row = (long long)blockIdx.x * 4 + wave;   // 16384 rows
  float2 v = ((const float2*)(x + row * DD))[lane];
  const double d0 = v.x, d1 = v.y;
  double s = d0 * d0 + d1 * d1;
  #pragma unroll
  for (int m = 32; m >= 1; m >>= 1) s += __shfl_xor(s, m, 64);
  double den = sqrt(s); den = den > 1e-12 ? den : 1e-12;
  if (lane == 0) rinv[row] = 1.0 / den;
  double2 o; o.x = d0 / den; o.y = d1 / den;
  u32 ux = __float_as_uint((float)o.x); ux = (ux + 0x7fffu + ((ux >> 16) & 1u)) >> 16;
  u32 uy = __float_as_uint((float)o.y); uy = (uy + 0x7fffu + ((uy >> 16) & 1u)) >> 16;
  nb[row * (DD / 2) + lane] = ux | (uy << 16);
}

// ---------------- fp32 top-8 value machinery ----------------
#define CXF(i, j) { const float a_ = L[i], b_ = L[j]; L[i] = fmaxf(a_, b_); L[j] = fminf(a_, b_); }
__device__ __forceinline__ void merge8f(float (&kv)[8], const float (&ov)[8]) {
  float L[8];
  #pragma unroll
  for (int i = 0; i < 8; ++i) L[i] = fmaxf(kv[i], ov[7 - i]);
  CXF(0, 4) CXF(1, 5) CXF(2, 6) CXF(3, 7)
  CXF(0, 2) CXF(1, 3) CXF(4, 6) CXF(5, 7)
  CXF(0, 1) CXF(2, 3) CXF(4, 5) CXF(6, 7)
  #pragma unroll
  for (int i = 0; i < 8; ++i) kv[i] = L[i];
}
__device__ __forceinline__ void insert8f(float (&v)[8], float nv) {
  if (nv > v[7]) {
    v[7] = nv;
    #pragma unroll
    for (int q = 7; q >= 1; --q) {
      const float a = v[q - 1], b = v[q];
      const bool sw = b > a;
      v[q - 1] = sw ? b : a; v[q] = sw ? a : b;
    }
  }
}

// ---------------- u64 exact-key machinery (validated R5-R14) ----------------
__device__ __forceinline__ u64 make_key(double s, int col) {
  u64 u = (u64)__double_as_longlong(s);
  const u64 m = (u64)((long long)u >> 63);
  u ^= (m | 0x8000000000000000ull);
  return (u & ~2047ull) | (u64)(2047 - col);
}
__device__ __forceinline__ u64 umax64(u64 a, u64 b) { return a > b ? a : b; }
__device__ __forceinline__ u64 umin64(u64 a, u64 b) { return a > b ? b : a; }
__device__ __forceinline__ void merge8(u64 (&kv)[8], const u64 (&ov)[8]) {
  u64 L[8];
  #pragma unroll
  for (int i = 0; i < 8; ++i) L[i] = umax64(kv[i], ov[7 - i]);
#define CX(i, j) { const u64 a_ = L[i], b_ = L[j]; L[i] = umax64(a_, b_); L[j] = umin64(a_, b_); }
  CX(0, 4) CX(1, 5) CX(2, 6) CX(3, 7)
  CX(0, 2) CX(1, 3) CX(4, 6) CX(5, 7)
  CX(0, 1) CX(2, 3) CX(4, 5) CX(6, 7)
#undef CX
  #pragma unroll
  for (int i = 0; i < 8; ++i) kv[i] = L[i];
}
__device__ __forceinline__ void insert8u(u64 (&v)[8], u64 nk) {
  if (nk > v[7]) {
    v[7] = nk;
    #pragma unroll
    for (int q = 7; q >= 1; --q) {
      const u64 a = v[q - 1], b = v[q];
      const bool sw = b > a;
      v[q - 1] = sw ? b : a; v[q] = sw ? a : b;
    }
  }
}

// ---------------- k_gram: bf16 Gram once, stream fp32 scores to ws ----------------
// grid 1024 = 256 rowblks x 4 col-splits; wave = 16 rows x 512 cols.
// Same calibrated MFMA structure as R11/R14's validated PassA — fold removed,
// scores written raw: lane's acc[p] = score(row0+rof, c0+16t+cof[p]).
__global__ __launch_bounds__(256) void k_gram(const u32* __restrict__ nb,
                                              float* __restrict__ scores) {
  const int tid = threadIdx.x; const int w = tid >> 6; const int l = tid & 63;
  const int q = l >> 4; const int m = l & 15;
  bf16x8 pvals = {0,0,0,0,0,0,0,0}, pones = {0,0,0,0,0,0,0,0};
  if (q == 0) {
    pvals[0] = (short)(__float_as_uint((float)(m + 1)) >> 16);
    pones[0] = (short)(__float_as_uint(1.0f) >> 16);
  }
  const f32x4 z4 = {0.0f, 0.0f, 0.0f, 0.0f};
  const f32x4 pr  = __builtin_amdgcn_mfma_f32_16x16x32_bf16(pvals, pones, z4, 0, 0, 0);
  const f32x4 pr2 = __builtin_amdgcn_mfma_f32_16x16x32_bf16(pones, pvals, z4, 0, 0, 0);
  int cof[4];
  #pragma unroll
  for (int p = 0; p < 4; ++p) cof[p] = (int)pr[p] - 1;
  const int rof = (int)pr2[0] - 1;
  const int rowblk = blockIdx.x >> 2; const int split = blockIdx.x & 3;
  const int row0 = rowblk * 64 + 16 * w;
  const int b = rowblk >> 5; const int c0 = split * 512;
  const u32* Bb = nb + ((long long)b * NN + c0) * (DD / 2);
  bf16x8 ar[4];
  { const u32* Ap = nb + (long long)(row0 + m) * (DD / 2) + 4 * q;
    #pragma unroll
    for (int cc = 0; cc < 4; ++cc) ar[cc] = *(const bf16x8*)(Ap + 16 * cc); }
  bf16x8 bcA[4], bcB[4];
  float* rowbase = scores + (long long)(row0 + rof) * NN + c0;

#define LOADB(DST, T) { const u32* p_ = Bb + (long long)(16 * (T) + m) * (DD / 2) + 4 * q; \
  _Pragma("unroll") for (int cc = 0; cc < 4; ++cc) DST[cc] = *(const bf16x8*)(p_ + 16 * cc); }
#define GEMM16(ACC, BC) { ACC = z4;                                                \
  _Pragma("unroll") for (int cc = 0; cc < 4; ++cc)                                 \
    ACC = __builtin_amdgcn_mfma_f32_16x16x32_bf16(BC[cc], ar[cc], ACC, 0, 0, 0); }
#define STORE4(ACC, T) { float* sp = rowbase + 16 * (T);                           \
    sp[cof[0]] = ACC[0]; sp[cof[1]] = ACC[1]; sp[cof[2]] = ACC[2]; sp[cof[3]] = ACC[3]; }

  LOADB(bcA, 0)
  for (int t = 0; t < 32; t += 2) {
    LOADB(bcB, t + 1)
    { f32x4 acc; GEMM16(acc, bcA) STORE4(acc, t) }
    if (t + 2 < 32) LOADB(bcA, t + 2)
    { f32x4 acc; GEMM16(acc, bcB) STORE4(acc, t + 1) }
  }
#undef LOADB
#undef GEMM16
#undef STORE4
}

// ---------------- k_rowtopk: per-row theta + survivor push (single score read) ----------------
// One wave per row; row's 2048 scores live in registers (32 floats/lane).
// theta/survivor semantics identical to R11/R14: theta = (8th largest approx) - MARGIN,
// survivors = { col : score >= theta }.
__global__ __launch_bounds__(256) void k_rowtopk(const float* __restrict__ scores,
                                                 u32* __restrict__ cnt,
                                                 u32* __restrict__ cand) {
  const int w = threadIdx.x >> 6, l = threadIdx.x & 63;
  const int r = blockIdx.x * 4 + w;            // 0..16383
  const float* row = scores + (long long)r * NN;
  float4 f[8];
  #pragma unroll
  for (int i = 0; i < 8; ++i) f[i] = ((const float4*)row)[i * 64 + l];

  float kv[8];
  #pragma unroll
  for (int s = 0; s < 8; ++s) kv[s] = -2.0f;
  #pragma unroll
  for (int i = 0; i < 8; ++i) {
    insert8f(kv, f[i].x); insert8f(kv, f[i].y);
    insert8f(kv, f[i].z); insert8f(kv, f[i].w);
  }
  // butterfly: all lanes converge to the row's top-8 values
  #pragma unroll
  for (int mk = 1; mk <= 32; mk <<= 1) {
    float ov[8];
    #pragma unroll
    for (int s = 0; s < 8; ++s) ov[s] = __shfl_xor(kv[s], mk, 64);
    merge8f(kv, ov);
  }
  const float th = kv[7] - MARGIN;

  // push survivors from registers (~10/row expected; CAP overflow -> exact fallback)
  #pragma unroll
  for (int i = 0; i < 8; ++i) {
    const int cb = 4 * (i * 64 + l);
    if (f[i].x >= th) { const u32 idx = atomicAdd(&cnt[r], 1u); if (idx < CAP) cand[(long long)r * CAP + idx] = (u32)(cb + 0); }
    if (f[i].y >= th) { const u32 idx = atomicAdd(&cnt[r], 1u); if (idx < CAP) cand[(long long)r * CAP + idx] = (u32)(cb + 1); }
    if (f[i].z >= th) { const u32 idx = atomicAdd(&cnt[r], 1u); if (idx < CAP) cand[(long long)r * CAP + idx] = (u32)(cb + 2); }
    if (f[i].w >= th) { const u32 idx = atomicAdd(&cnt[r], 1u); if (idx < CAP) cand[(long long)r * CAP + idx] = (u32)(cb + 3); }
  }
}

// ---------------- k_exact: fp64 rescore from fp32 x (validated R14) ----------------
__global__ __launch_bounds__(256) void k_exact(const float* __restrict__ x,
                                               const double* __restrict__ rinv,
                                               const u32* __restrict__ cnt,
                                               const u32* __restrict__ cand,
                                               float* __restrict__ out) {
  const int w = threadIdx.x >> 6, l = threadIdx.x & 63;
  const int r = blockIdx.x * 4 + w;            // 0..16383
  const int n = r & (NN - 1);
  const long long brow = r - n;                // b*NN
  const float2 a2 = ((const float2*)(x + (long long)r * DD))[l];
  const double ri = rinv[r];
  const int c = (int)cnt[r];
  u64 kv[8];
  #pragma unroll
  for (int s = 0; s < 8; ++s) kv[s] = 0ull;

  if (c <= CAP) {
    for (int i = 0; i < c; i += 4) {
      float2 vv[4]; int col[4];
      #pragma unroll
      for (int g = 0; g < 4; ++g) {
        const int idx = i + g;
        col[g] = (idx < c) ? ((int)cand[(long long)r * CAP + idx] & (NN - 1)) : 0;
        vv[g] = ((const float2*)(x + (brow + col[g]) * DD))[l];
      }
      #pragma unroll
      for (int g = 0; g < 4; ++g) {
        double d = fma((double)a2.x, (double)vv[g].x, (double)a2.y * (double)vv[g].y);
        #pragma unroll
        for (int mk = 1; mk <= 32; mk <<= 1) d += __shfl_xor(d, mk, 64);
        if (i + g < c) insert8u(kv, make_key(d * ri * rinv[brow + col[g]], col[g]));
      }
    }
  } else {
    // overflow fallback (never expected): full exact row scan
    for (int base = 0; base < NN; base += 64) {
      const int col = base + l;
      const float* ap = x + (long long)r * DD;
      const float* cp = x + (brow + col) * DD;
      double d = 0.0;
      for (int kk = 0; kk < 64; ++kk) {
        const float2 av = ((const float2*)ap)[kk];
        const float2 bv = ((const float2*)cp)[kk];
        d = fma((double)av.x, (double)bv.x, fma((double)av.y, (double)bv.y, d));
      }
      d = d * ri * rinv[brow + col];
      u64 one[8];
      one[0] = make_key(d, col);
      #pragma unroll
      for (int s = 1; s < 8; ++s) one[s] = 0ull;
      #pragma unroll
      for (int mk = 1; mk <= 32; mk <<= 1) {
        u64 ov[8];
        #pragma unroll
        for (int s = 0; s < 8; ++s) ov[s] = __shfl_xor(one[s], mk, 64);
        merge8(one, ov);
      }
      merge8(kv, one);
    }
  }

  const long long orow = (long long)r * NN;
  const long long obase = brow * NN;           // b*NN*NN
  if (l == 8) out[orow + n] = 1.0f;            // self loop
  #pragma unroll
  for (int s = 0; s < 8; ++s) {
    const int mcol = 2047 - (int)(kv[s] & 2047ull);
    if (l == s) {
      out[orow + mcol] = 1.0f;
      out[obase + (long long)mcol * NN + n] = 1.0f;
    }
  }
}

extern "C" void kernel_launch(void* const* d_in, const int* in_sizes, int n_in,
                              void* d_out, int out_size, void* d_ws, size_t ws_size,
                              hipStream_t stream) {
  const float* x = (const float*)d_in[0];
  float* out = (float*)d_out;
  char* ws = (char*)d_ws;
  u32* nb = (u32*)ws;                                //  4,194,304 B (bf16 normed)
  double* rinv = (double*)(ws + 4194304);            //    131,072 B
  u32* cnt = (u32*)(ws + 4325376);                   //     65,536 B
  u32* cand = (u32*)(ws + 4390912);                  //  4,194,304 B (16384 x 64)
  float* scores = (float*)(ws + 8585216);            // 134,217,728 B (ws >= 512 MiB per profile)

  hipMemsetAsync(d_out, 0, (size_t)out_size * sizeof(float), stream);
  hipMemsetAsync(cnt, 0, NROWS * sizeof(u32), stream);
  hipLaunchKernelGGL(k_normalize, dim3(NROWS / 4), dim3(256), 0, stream, x, rinv, nb);
  hipLaunchKernelGGL(k_gram, dim3(1024), dim3(256), 0, stream, nb, scores);
  hipLaunchKernelGGL(k_rowtopk, dim3(NROWS / 4), dim3(256), 0, stream, scores, cnt, cand);
  hipLaunchKernelGGL(k_exact, dim3(NROWS / 4), dim3(256), 0, stream, x, rinv, cnt, cand, out);
}

// Round 16
// 320.946 us; speedup vs baseline: 1.1035x; 1.1035x over previous
//
#include <hip/hip_runtime.h>
#include <cstdint>

#define NN 2048
#define DD 128
#define BATCH 8
#define NROWS 16384
#define MARGIN 0.02f     // >= 2.5x the rigorous 2E bound (E<0.004: bf16 2^-8 + fp32-acc)
#define CAP 64

typedef __attribute__((ext_vector_type(8))) short bf16x8;
typedef __attribute__((ext_vector_type(4))) float f32x4;
typedef unsigned long long u64;
typedef unsigned int u32;

// ---------------- K1: norms + bf16 normalized copy + cnt zero (validated R14/R15) ----------------
__global__ __launch_bounds__(256) void k_normalize(const float* __restrict__ x,
                                                   double* __restrict__ rinv,
                                                   u32* __restrict__ nb,
                                                   u32* __restrict__ cnt) {
  const int wave = threadIdx.x >> 6, lane = threadIdx.x & 63;
  const long long row = (long long)blockIdx.x * 4 + wave;   // 16384 rows
  // fold cnt zeroing into this kernel (saves one dispatch)
  const int gid = blockIdx.x * 256 + threadIdx.x;
  if (gid < NROWS) cnt[gid] = 0u;
  float2 v = ((const float2*)(x + row * DD))[lane];
  const double d0 = v.x, d1 = v.y;
  double s = d0 * d0 + d1 * d1;
  #pragma unroll
  for (int m = 32; m >= 1; m >>= 1) s += __shfl_xor(s, m, 64);
  double den = sqrt(s); den = den > 1e-12 ? den : 1e-12;
  if (lane == 0) rinv[row] = 1.0 / den;
  double2 o; o.x = d0 / den; o.y = d1 / den;
  u32 ux = __float_as_uint((float)o.x); ux = (ux + 0x7fffu + ((ux >> 16) & 1u)) >> 16;
  u32 uy = __float_as_uint((float)o.y); uy = (uy + 0x7fffu + ((uy >> 16) & 1u)) >> 16;
  nb[row * (DD / 2) + lane] = ux | (uy << 16);
}

// ---------------- fp32 top-8 value machinery ----------------
#define CXF(i, j) { const float a_ = L[i], b_ = L[j]; L[i] = fmaxf(a_, b_); L[j] = fminf(a_, b_); }
__device__ __forceinline__ void merge8f(float (&kv)[8], const float (&ov)[8]) {
  float L[8];
  #pragma unroll
  for (int i = 0; i < 8; ++i) L[i] = fmaxf(kv[i], ov[7 - i]);
  CXF(0, 4) CXF(1, 5) CXF(2, 6) CXF(3, 7)
  CXF(0, 2) CXF(1, 3) CXF(4, 6) CXF(5, 7)
  CXF(0, 1) CXF(2, 3) CXF(4, 5) CXF(6, 7)
  #pragma unroll
  for (int i = 0; i < 8; ++i) kv[i] = L[i];
}
__device__ __forceinline__ void insert8f(float (&v)[8], float nv) {
  if (nv > v[7]) {
    v[7] = nv;
    #pragma unroll
    for (int q = 7; q >= 1; --q) {
      const float a = v[q - 1], b = v[q];
      const bool sw = b > a;
      v[q - 1] = sw ? b : a; v[q] = sw ? a : b;
    }
  }
}

// ---------------- u64 exact-key machinery (validated R5-R15) ----------------
__device__ __forceinline__ u64 make_key(double s, int col) {
  u64 u = (u64)__double_as_longlong(s);
  const u64 m = (u64)((long long)u >> 63);
  u ^= (m | 0x8000000000000000ull);
  return (u & ~2047ull) | (u64)(2047 - col);
}
__device__ __forceinline__ u64 umax64(u64 a, u64 b) { return a > b ? a : b; }
__device__ __forceinline__ u64 umin64(u64 a, u64 b) { return a > b ? b : a; }
__device__ __forceinline__ void merge8(u64 (&kv)[8], const u64 (&ov)[8]) {
  u64 L[8];
  #pragma unroll
  for (int i = 0; i < 8; ++i) L[i] = umax64(kv[i], ov[7 - i]);
#define CX(i, j) { const u64 a_ = L[i], b_ = L[j]; L[i] = umax64(a_, b_); L[j] = umin64(a_, b_); }
  CX(0, 4) CX(1, 5) CX(2, 6) CX(3, 7)
  CX(0, 2) CX(1, 3) CX(4, 6) CX(5, 7)
  CX(0, 1) CX(2, 3) CX(4, 5) CX(6, 7)
#undef CX
  #pragma unroll
  for (int i = 0; i < 8; ++i) kv[i] = L[i];
}
__device__ __forceinline__ void insert8u(u64 (&v)[8], u64 nk) {
  if (nk > v[7]) {
    v[7] = nk;
    #pragma unroll
    for (int q = 7; q >= 1; --q) {
      const u64 a = v[q - 1], b = v[q];
      const bool sw = b > a;
      v[q - 1] = sw ? b : a; v[q] = sw ? a : b;
    }
  }
}

// ---------------- k_gram: bf16 Gram once, stream fp32 scores (vectorized stores) ----------------
// grid 1024 = 256 rowblks x 4 col-splits; wave = 16 rows x 512 cols.
// R16 fix: calibrated cof[] is contiguous (cof[p]=4q+p per m89 layout) -> runtime
// wave-uniform check enables float4 stores (R15's scalar stores ran at 1.4 TB/s).
__global__ __launch_bounds__(256) void k_gram(const u32* __restrict__ nb,
                                              float* __restrict__ scores) {
  const int tid = threadIdx.x; const int w = tid >> 6; const int l = tid & 63;
  const int q = l >> 4; const int m = l & 15;
  bf16x8 pvals = {0,0,0,0,0,0,0,0}, pones = {0,0,0,0,0,0,0,0};
  if (q == 0) {
    pvals[0] = (short)(__float_as_uint((float)(m + 1)) >> 16);
    pones[0] = (short)(__float_as_uint(1.0f) >> 16);
  }
  const f32x4 z4 = {0.0f, 0.0f, 0.0f, 0.0f};
  const f32x4 pr  = __builtin_amdgcn_mfma_f32_16x16x32_bf16(pvals, pones, z4, 0, 0, 0);
  const f32x4 pr2 = __builtin_amdgcn_mfma_f32_16x16x32_bf16(pones, pvals, z4, 0, 0, 0);
  int cof[4];
  #pragma unroll
  for (int p = 0; p < 4; ++p) cof[p] = (int)pr[p] - 1;
  const int rof = (int)pr2[0] - 1;
  const bool contig = (cof[1] == cof[0] + 1) && (cof[2] == cof[0] + 2) &&
                      (cof[3] == cof[0] + 3) && ((cof[0] & 3) == 0);
  const int rowblk = blockIdx.x >> 2; const int split = blockIdx.x & 3;
  const int row0 = rowblk * 64 + 16 * w;
  const int b = rowblk >> 5; const int c0 = split * 512;
  const u32* Bb = nb + ((long long)b * NN + c0) * (DD / 2);
  bf16x8 ar[4];
  { const u32* Ap = nb + (long long)(row0 + m) * (DD / 2) + 4 * q;
    #pragma unroll
    for (int cc = 0; cc < 4; ++cc) ar[cc] = *(const bf16x8*)(Ap + 16 * cc); }
  bf16x8 bcA[4], bcB[4];
  float* rowbase = scores + (long long)(row0 + rof) * NN + c0;

#define LOADB(DST, T) { const u32* p_ = Bb + (long long)(16 * (T) + m) * (DD / 2) + 4 * q; \
  _Pragma("unroll") for (int cc = 0; cc < 4; ++cc) DST[cc] = *(const bf16x8*)(p_ + 16 * cc); }
#define GEMM16(ACC, BC) { ACC = z4;                                                \
  _Pragma("unroll") for (int cc = 0; cc < 4; ++cc)                                 \
    ACC = __builtin_amdgcn_mfma_f32_16x16x32_bf16(BC[cc], ar[cc], ACC, 0, 0, 0); }
#define STORE4(ACC, T) { float* sp = rowbase + 16 * (T);                           \
    if (contig) {                                                                  \
      float4 sv; sv.x = ACC[0]; sv.y = ACC[1]; sv.z = ACC[2]; sv.w = ACC[3];       \
      *(float4*)(sp + cof[0]) = sv;                                                \
    } else {                                                                       \
      sp[cof[0]] = ACC[0]; sp[cof[1]] = ACC[1];                                    \
      sp[cof[2]] = ACC[2]; sp[cof[3]] = ACC[3];                                    \
    } }

  LOADB(bcA, 0)
  for (int t = 0; t < 32; t += 2) {
    LOADB(bcB, t + 1)
    { f32x4 acc; GEMM16(acc, bcA) STORE4(acc, t) }
    if (t + 2 < 32) LOADB(bcA, t + 2)
    { f32x4 acc; GEMM16(acc, bcB) STORE4(acc, t + 1) }
  }
#undef LOADB
#undef GEMM16
#undef STORE4
}

// ---------------- k_rowtopk: per-row theta + survivor push (dual insert chains) ----------------
__global__ __launch_bounds__(256) void k_rowtopk(const float* __restrict__ scores,
                                                 u32* __restrict__ cnt,
                                                 u32* __restrict__ cand) {
  const int w = threadIdx.x >> 6, l = threadIdx.x & 63;
  const int r = blockIdx.x * 4 + w;            // 0..16383
  const float* row = scores + (long long)r * NN;
  float4 f[8];
  #pragma unroll
  for (int i = 0; i < 8; ++i) f[i] = ((const float4*)row)[i * 64 + l];

  // two independent insert chains (R16: halves the serial dependency depth)
  float kva[8], kvb[8];
  #pragma unroll
  for (int s = 0; s < 8; ++s) { kva[s] = -2.0f; kvb[s] = -2.0f; }
  #pragma unroll
  for (int i = 0; i < 8; i += 2) {
    insert8f(kva, f[i].x);     insert8f(kvb, f[i + 1].x);
    insert8f(kva, f[i].y);     insert8f(kvb, f[i + 1].y);
    insert8f(kva, f[i].z);     insert8f(kvb, f[i + 1].z);
    insert8f(kva, f[i].w);     insert8f(kvb, f[i + 1].w);
  }
  merge8f(kva, kvb);
  // butterfly: all lanes converge to the row's top-8 values
  #pragma unroll
  for (int mk = 1; mk <= 32; mk <<= 1) {
    float ov[8];
    #pragma unroll
    for (int s = 0; s < 8; ++s) ov[s] = __shfl_xor(kva[s], mk, 64);
    merge8f(kva, ov);
  }
  const float th = kva[7] - MARGIN;

  // push survivors from registers (~10/row expected; CAP overflow -> exact fallback)
  #pragma unroll
  for (int i = 0; i < 8; ++i) {
    const int cb = 4 * (i * 64 + l);
    if (f[i].x >= th) { const u32 idx = atomicAdd(&cnt[r], 1u); if (idx < CAP) cand[(long long)r * CAP + idx] = (u32)(cb + 0); }
    if (f[i].y >= th) { const u32 idx = atomicAdd(&cnt[r], 1u); if (idx < CAP) cand[(long long)r * CAP + idx] = (u32)(cb + 1); }
    if (f[i].z >= th) { const u32 idx = atomicAdd(&cnt[r], 1u); if (idx < CAP) cand[(long long)r * CAP + idx] = (u32)(cb + 2); }
    if (f[i].w >= th) { const u32 idx = atomicAdd(&cnt[r], 1u); if (idx < CAP) cand[(long long)r * CAP + idx] = (u32)(cb + 3); }
  }
}

// ---------------- k_exact: fp64 rescore from fp32 x (validated R14/R15) ----------------
__global__ __launch_bounds__(256) void k_exact(const float* __restrict__ x,
                                               const double* __restrict__ rinv,
                                               const u32* __restrict__ cnt,
                                               const u32* __restrict__ cand,
                                               float* __restrict__ out) {
  const int w = threadIdx.x >> 6, l = threadIdx.x & 63;
  const int r = blockIdx.x * 4 + w;            // 0..16383
  const int n = r & (NN - 1);
  const long long brow = r - n;                // b*NN
  const float2 a2 = ((const float2*)(x + (long long)r * DD))[l];
  const double ri = rinv[r];
  const int c = (int)cnt[r];
  u64 kv[8];
  #pragma unroll
  for (int s = 0; s < 8; ++s) kv[s] = 0ull;

  if (c <= CAP) {
    for (int i = 0; i < c; i += 4) {
      float2 vv[4]; int col[4];
      #pragma unroll
      for (int g = 0; g < 4; ++g) {
        const int idx = i + g;
        col[g] = (idx < c) ? ((int)cand[(long long)r * CAP + idx] & (NN - 1)) : 0;
        vv[g] = ((const float2*)(x + (brow + col[g]) * DD))[l];
      }
      #pragma unroll
      for (int g = 0; g < 4; ++g) {
        double d = fma((double)a2.x, (double)vv[g].x, (double)a2.y * (double)vv[g].y);
        #pragma unroll
        for (int mk = 1; mk <= 32; mk <<= 1) d += __shfl_xor(d, mk, 64);
        if (i + g < c) insert8u(kv, make_key(d * ri * rinv[brow + col[g]], col[g]));
      }
    }
  } else {
    // overflow fallback (never expected): full exact row scan
    for (int base = 0; base < NN; base += 64) {
      const int col = base + l;
      const float* ap = x + (long long)r * DD;
      const float* cp = x + (brow + col) * DD;
      double d = 0.0;
      for (int kk = 0; kk < 64; ++kk) {
        const float2 av = ((const float2*)ap)[kk];
        const float2 bv = ((const float2*)cp)[kk];
        d = fma((double)av.x, (double)bv.x, fma((double)av.y, (double)bv.y, d));
      }
      d = d * ri * rinv[brow + col];
      u64 one[8];
      one[0] = make_key(d, col);
      #pragma unroll
      for (int s = 1; s < 8; ++s) one[s] = 0ull;
      #pragma unroll
      for (int mk = 1; mk <= 32; mk <<= 1) {
        u64 ov[8];
        #pragma unroll
        for (int s = 0; s < 8; ++s) ov[s] = __shfl_xor(one[s], mk, 64);
        merge8(one, ov);
      }
      merge8(kv, one);
    }
  }

  const long long orow = (long long)r * NN;
  const long long obase = brow * NN;           // b*NN*NN
  if (l == 8) out[orow + n] = 1.0f;            // self loop
  #pragma unroll
  for (int s = 0; s < 8; ++s) {
    const int mcol = 2047 - (int)(kv[s] & 2047ull);
    if (l == s) {
      out[orow + mcol] = 1.0f;
      out[obase + (long long)mcol * NN + n] = 1.0f;
    }
  }
}

extern "C" void kernel_launch(void* const* d_in, const int* in_sizes, int n_in,
                              void* d_out, int out_size, void* d_ws, size_t ws_size,
                              hipStream_t stream) {
  const float* x = (const float*)d_in[0];
  float* out = (float*)d_out;
  char* ws = (char*)d_ws;
  u32* nb = (u32*)ws;                                //  4,194,304 B (bf16 normed)
  double* rinv = (double*)(ws + 4194304);            //    131,072 B
  u32* cnt = (u32*)(ws + 4325376);                   //     65,536 B
  u32* cand = (u32*)(ws + 4390912);                  //  4,194,304 B (16384 x 64)
  float* scores = (float*)(ws + 8585216);            // 134,217,728 B

  hipMemsetAsync(d_out, 0, (size_t)out_size * sizeof(float), stream);
  hipLaunchKernelGGL(k_normalize, dim3(NROWS / 4), dim3(256), 0, stream, x, rinv, nb, cnt);
  hipLaunchKernelGGL(k_gram, dim3(1024), dim3(256), 0, stream, nb, scores);
  hipLaunchKernelGGL(k_rowtopk, dim3(NROWS / 4), dim3(256), 0, stream, scores, cnt, cand);
  hipLaunchKernelGGL(k_exact, dim3(NROWS / 4), dim3(256), 0, stream, x, rinv, cnt, cand, out);
}

// Round 17
// 290.908 us; speedup vs baseline: 1.2174x; 1.1033x over previous
//
#include <hip/hip_runtime.h>
#include <cstdint>

#define NN 2048
#define DD 128
#define BATCH 8
#define NROWS 16384
#define MARGIN 0.02f     // rigorous need: 2E + 2*bf16-half-ulp = 0.008 + 0.004 = 0.012
#define CAP 64

typedef __attribute__((ext_vector_type(8))) short bf16x8;
typedef __attribute__((ext_vector_type(4))) float f32x4;
typedef unsigned long long u64;
typedef unsigned int u32;
typedef unsigned short u16;

__device__ __forceinline__ u32 bf16rne(float f) {
  u32 u = __float_as_uint(f);
  return (u + 0x7fffu + ((u >> 16) & 1u)) >> 16;
}

// ---------------- K1: norms + bf16 normalized copy (validated R14-R16) ----------------
__global__ __launch_bounds__(256) void k_normalize(const float* __restrict__ x,
                                                   double* __restrict__ rinv,
                                                   u32* __restrict__ nb) {
  const int wave = threadIdx.x >> 6, lane = threadIdx.x & 63;
  const long long row = (long long)blockIdx.x * 4 + wave;   // 16384 rows
  float2 v = ((const float2*)(x + row * DD))[lane];
  const double d0 = v.x, d1 = v.y;
  double s = d0 * d0 + d1 * d1;
  #pragma unroll
  for (int m = 32; m >= 1; m >>= 1) s += __shfl_xor(s, m, 64);
  double den = sqrt(s); den = den > 1e-12 ? den : 1e-12;
  if (lane == 0) rinv[row] = 1.0 / den;
  double2 o; o.x = d0 / den; o.y = d1 / den;
  nb[row * (DD / 2) + lane] = bf16rne((float)o.x) | (bf16rne((float)o.y) << 16);
}

// ---------------- fp32 top-8 value machinery (validated R15/R16) ----------------
#define CXF(i, j) { const float a_ = L[i], b_ = L[j]; L[i] = fmaxf(a_, b_); L[j] = fminf(a_, b_); }
__device__ __forceinline__ void merge8f(float (&kv)[8], const float (&ov)[8]) {
  float L[8];
  #pragma unroll
  for (int i = 0; i < 8; ++i) L[i] = fmaxf(kv[i], ov[7 - i]);
  CXF(0, 4) CXF(1, 5) CXF(2, 6) CXF(3, 7)
  CXF(0, 2) CXF(1, 3) CXF(4, 6) CXF(5, 7)
  CXF(0, 1) CXF(2, 3) CXF(4, 5) CXF(6, 7)
  #pragma unroll
  for (int i = 0; i < 8; ++i) kv[i] = L[i];
}
__device__ __forceinline__ void insert8f(float (&v)[8], float nv) {
  if (nv > v[7]) {
    v[7] = nv;
    #pragma unroll
    for (int q = 7; q >= 1; --q) {
      const float a = v[q - 1], b = v[q];
      const bool sw = b > a;
      v[q - 1] = sw ? b : a; v[q] = sw ? a : b;
    }
  }
}

// ---------------- u64 exact-key machinery (validated R5-R16) ----------------
__device__ __forceinline__ u64 make_key(double s, int col) {
  u64 u = (u64)__double_as_longlong(s);
  const u64 m = (u64)((long long)u >> 63);
  u ^= (m | 0x8000000000000000ull);
  return (u & ~2047ull) | (u64)(2047 - col);
}
__device__ __forceinline__ u64 umax64(u64 a, u64 b) { return a > b ? a : b; }
__device__ __forceinline__ u64 umin64(u64 a, u64 b) { return a > b ? b : a; }
__device__ __forceinline__ void merge8(u64 (&kv)[8], const u64 (&ov)[8]) {
  u64 L[8];
  #pragma unroll
  for (int i = 0; i < 8; ++i) L[i] = umax64(kv[i], ov[7 - i]);
#define CX(i, j) { const u64 a_ = L[i], b_ = L[j]; L[i] = umax64(a_, b_); L[j] = umin64(a_, b_); }
  CX(0, 4) CX(1, 5) CX(2, 6) CX(3, 7)
  CX(0, 2) CX(1, 3) CX(4, 6) CX(5, 7)
  CX(0, 1) CX(2, 3) CX(4, 5) CX(6, 7)
#undef CX
  #pragma unroll
  for (int i = 0; i < 8; ++i) kv[i] = L[i];
}
__device__ __forceinline__ void insert8u(u64 (&v)[8], u64 nk) {
  if (nk > v[7]) {
    v[7] = nk;
    #pragma unroll
    for (int q = 7; q >= 1; --q) {
      const u64 a = v[q - 1], b = v[q];
      const bool sw = b > a;
      v[q - 1] = sw ? b : a; v[q] = sw ? a : b;
    }
  }
}

// ---------------- k_gram: bf16 Gram once, stream bf16 scores (uint2 stores) ----------------
// grid 1024 = 256 rowblks x 4 col-splits; wave = 16 rows x 512 cols.
// R17: scores stored as bf16 pairs (halves write traffic vs R16's fp32).
__global__ __launch_bounds__(256) void k_gram(const u32* __restrict__ nb,
                                              u16* __restrict__ scores) {
  const int tid = threadIdx.x; const int w = tid >> 6; const int l = tid & 63;
  const int q = l >> 4; const int m = l & 15;
  bf16x8 pvals = {0,0,0,0,0,0,0,0}, pones = {0,0,0,0,0,0,0,0};
  if (q == 0) {
    pvals[0] = (short)(__float_as_uint((float)(m + 1)) >> 16);
    pones[0] = (short)(__float_as_uint(1.0f) >> 16);
  }
  const f32x4 z4 = {0.0f, 0.0f, 0.0f, 0.0f};
  const f32x4 pr  = __builtin_amdgcn_mfma_f32_16x16x32_bf16(pvals, pones, z4, 0, 0, 0);
  const f32x4 pr2 = __builtin_amdgcn_mfma_f32_16x16x32_bf16(pones, pvals, z4, 0, 0, 0);
  int cof[4];
  #pragma unroll
  for (int p = 0; p < 4; ++p) cof[p] = (int)pr[p] - 1;
  const int rof = (int)pr2[0] - 1;
  const bool contig = (cof[1] == cof[0] + 1) && (cof[2] == cof[0] + 2) &&
                      (cof[3] == cof[0] + 3) && ((cof[0] & 3) == 0);
  const int rowblk = blockIdx.x >> 2; const int split = blockIdx.x & 3;
  const int row0 = rowblk * 64 + 16 * w;
  const int b = rowblk >> 5; const int c0 = split * 512;
  const u32* Bb = nb + ((long long)b * NN + c0) * (DD / 2);
  bf16x8 ar[4];
  { const u32* Ap = nb + (long long)(row0 + m) * (DD / 2) + 4 * q;
    #pragma unroll
    for (int cc = 0; cc < 4; ++cc) ar[cc] = *(const bf16x8*)(Ap + 16 * cc); }
  bf16x8 bcA[4], bcB[4];
  u16* rowbase = scores + (long long)(row0 + rof) * NN + c0;

#define LOADB(DST, T) { const u32* p_ = Bb + (long long)(16 * (T) + m) * (DD / 2) + 4 * q; \
  _Pragma("unroll") for (int cc = 0; cc < 4; ++cc) DST[cc] = *(const bf16x8*)(p_ + 16 * cc); }
#define GEMM16(ACC, BC) { ACC = z4;                                                \
  _Pragma("unroll") for (int cc = 0; cc < 4; ++cc)                                 \
    ACC = __builtin_amdgcn_mfma_f32_16x16x32_bf16(BC[cc], ar[cc], ACC, 0, 0, 0); }
#define STORE4(ACC, T) { u16* sp = rowbase + 16 * (T);                             \
    if (contig) {                                                                  \
      uint2 sv;                                                                    \
      sv.x = bf16rne(ACC[0]) | (bf16rne(ACC[1]) << 16);                            \
      sv.y = bf16rne(ACC[2]) | (bf16rne(ACC[3]) << 16);                            \
      *(uint2*)(sp + cof[0]) = sv;                                                 \
    } else {                                                                       \
      sp[cof[0]] = (u16)bf16rne(ACC[0]); sp[cof[1]] = (u16)bf16rne(ACC[1]);        \
      sp[cof[2]] = (u16)bf16rne(ACC[2]); sp[cof[3]] = (u16)bf16rne(ACC[3]);        \
    } }

  LOADB(bcA, 0)
  for (int t = 0; t < 32; t += 2) {
    LOADB(bcB, t + 1)
    { f32x4 acc; GEMM16(acc, bcA) STORE4(acc, t) }
    if (t + 2 < 32) LOADB(bcA, t + 2)
    { f32x4 acc; GEMM16(acc, bcB) STORE4(acc, t + 1) }
  }
#undef LOADB
#undef GEMM16
#undef STORE4
}

// ---------------- k_topk_exact: fused theta + survivor push (LDS) + fp64 rescore ----------------
// One wave per row. theta/survivor semantics identical to validated R15/R16 rowtopk
// (comparisons on the bf16-rounded scores, consistently); rescore/scatter identical
// to validated R14-R16 k_exact with LDS candidate source.
__global__ __launch_bounds__(256) void k_topk_exact(const u16* __restrict__ scores,
                                                    const float* __restrict__ x,
                                                    const double* __restrict__ rinv,
                                                    float* __restrict__ out) {
  __shared__ u32 scnt[4];
  __shared__ u32 scand[4][CAP];

  const int w = threadIdx.x >> 6, l = threadIdx.x & 63;
  const int r = blockIdx.x * 4 + w;            // 0..16383
  const int n = r & (NN - 1);
  const long long brow = r - n;                // b*NN

  if (l == 0) scnt[w] = 0u;                    // wave-local; LDS in-order, no barrier

  // load the row's 2048 bf16 scores: 4 x uint4 = 32 scores/lane, coalesced
  const u32* row32 = (const u32*)(scores + (long long)r * NN);
  uint4 rv[4];
  #pragma unroll
  for (int i = 0; i < 4; ++i) rv[i] = ((const uint4*)row32)[i * 64 + l];

  float fs[32];
  #pragma unroll
  for (int i = 0; i < 4; ++i)
    #pragma unroll
    for (int c = 0; c < 4; ++c) {
      const u32 u = (&rv[i].x)[c];
      fs[i * 8 + 2 * c]     = __uint_as_float(u << 16);
      fs[i * 8 + 2 * c + 1] = __uint_as_float(u & 0xFFFF0000u);
    }

  // dual-chain fold (validated R16) -> row top-8 values
  float kva[8], kvb[8];
  #pragma unroll
  for (int s = 0; s < 8; ++s) { kva[s] = -2.0f; kvb[s] = -2.0f; }
  #pragma unroll
  for (int j = 0; j < 16; ++j) { insert8f(kva, fs[j]); insert8f(kvb, fs[16 + j]); }
  merge8f(kva, kvb);
  #pragma unroll
  for (int mk = 1; mk <= 32; mk <<= 1) {
    float ov[8];
    #pragma unroll
    for (int s = 0; s < 8; ++s) ov[s] = __shfl_xor(kva[s], mk, 64);
    merge8f(kva, ov);
  }
  const float th = kva[7] - MARGIN;

  // push survivors into the wave's LDS buffer (~10/row expected)
  #pragma unroll
  for (int i = 0; i < 4; ++i)
    #pragma unroll
    for (int c = 0; c < 4; ++c) {
      const int colb = 8 * (i * 64 + l) + 2 * c;
      if (fs[i * 8 + 2 * c] >= th) {
        const u32 idx = atomicAdd(&scnt[w], 1u);
        if (idx < CAP) scand[w][idx] = (u32)colb;
      }
      if (fs[i * 8 + 2 * c + 1] >= th) {
        const u32 idx = atomicAdd(&scnt[w], 1u);
        if (idx < CAP) scand[w][idx] = (u32)(colb + 1);
      }
    }

  const int c = (int)scnt[w];                  // wave-lockstep: all pushes complete
  const float2 a2 = ((const float2*)(x + (long long)r * DD))[l];
  const double ri = rinv[r];
  u64 kv[8];
  #pragma unroll
  for (int s = 0; s < 8; ++s) kv[s] = 0ull;

  if (c <= CAP) {
    for (int i = 0; i < c; i += 4) {
      float2 vv[4]; int col[4];
      #pragma unroll
      for (int g = 0; g < 4; ++g) {
        const int idx = i + g;
        col[g] = (idx < c) ? ((int)scand[w][idx] & (NN - 1)) : 0;
        vv[g] = ((const float2*)(x + (brow + col[g]) * DD))[l];
      }
      #pragma unroll
      for (int g = 0; g < 4; ++g) {
        double d = fma((double)a2.x, (double)vv[g].x, (double)a2.y * (double)vv[g].y);
        #pragma unroll
        for (int mk = 1; mk <= 32; mk <<= 1) d += __shfl_xor(d, mk, 64);
        if (i + g < c) insert8u(kv, make_key(d * ri * rinv[brow + col[g]], col[g]));
      }
    }
  } else {
    // overflow fallback (never expected): full exact row scan (validated)
    for (int base = 0; base < NN; base += 64) {
      const int col = base + l;
      const float* ap = x + (long long)r * DD;
      const float* cp = x + (brow + col) * DD;
      double d = 0.0;
      for (int kk = 0; kk < 64; ++kk) {
        const float2 av = ((const float2*)ap)[kk];
        const float2 bv = ((const float2*)cp)[kk];
        d = fma((double)av.x, (double)bv.x, fma((double)av.y, (double)bv.y, d));
      }
      d = d * ri * rinv[brow + col];
      u64 one[8];
      one[0] = make_key(d, col);
      #pragma unroll
      for (int s = 1; s < 8; ++s) one[s] = 0ull;
      #pragma unroll
      for (int mk = 1; mk <= 32; mk <<= 1) {
        u64 ov[8];
        #pragma unroll
        for (int s = 0; s < 8; ++s) ov[s] = __shfl_xor(one[s], mk, 64);
        merge8(one, ov);
      }
      merge8(kv, one);
    }
  }

  const long long orow = (long long)r * NN;
  const long long obase = brow * NN;           // b*NN*NN
  if (l == 8) out[orow + n] = 1.0f;            // self loop
  #pragma unroll
  for (int s = 0; s < 8; ++s) {
    const int mcol = 2047 - (int)(kv[s] & 2047ull);
    if (l == s) {
      out[orow + mcol] = 1.0f;
      out[obase + (long long)mcol * NN + n] = 1.0f;
    }
  }
}

extern "C" void kernel_launch(void* const* d_in, const int* in_sizes, int n_in,
                              void* d_out, int out_size, void* d_ws, size_t ws_size,
                              hipStream_t stream) {
  const float* x = (const float*)d_in[0];
  float* out = (float*)d_out;
  char* ws = (char*)d_ws;
  u32* nb = (u32*)ws;                                //  4,194,304 B (bf16 normed)
  double* rinv = (double*)(ws + 4194304);            //    131,072 B
  u16* scores = (u16*)(ws + 4325376);                // 67,108,864 B (bf16 scores)

  hipMemsetAsync(d_out, 0, (size_t)out_size * sizeof(float), stream);
  hipLaunchKernelGGL(k_normalize, dim3(NROWS / 4), dim3(256), 0, stream, x, rinv, nb);
  hipLaunchKernelGGL(k_gram, dim3(1024), dim3(256), 0, stream, nb, scores);
  hipLaunchKernelGGL(k_topk_exact, dim3(NROWS / 4), dim3(256), 0, stream, scores, x, rinv, out);
}

// Round 18
// 279.550 us; speedup vs baseline: 1.2669x; 1.0406x over previous
//
#include <hip/hip_runtime.h>
#include <cstdint>

#define NN 2048
#define DD 128
#define BATCH 8
#define NROWS 16384
#define MARGIN 0.02f     // rigorous need: 2E + 2*bf16-half-ulp = 0.008 + 0.004 = 0.012
#define CAP 64

typedef __attribute__((ext_vector_type(8))) short bf16x8;
typedef __attribute__((ext_vector_type(4))) float f32x4;
typedef unsigned long long u64;
typedef unsigned int u32;
typedef unsigned short u16;

__device__ __forceinline__ u32 bf16rne(float f) {
  u32 u = __float_as_uint(f);
  return (u + 0x7fffu + ((u >> 16) & 1u)) >> 16;
}

// ---------------- K1: norms + bf16 normalized copy (validated R14-R17) ----------------
__global__ __launch_bounds__(256) void k_normalize(const float* __restrict__ x,
                                                   double* __restrict__ rinv,
                                                   u32* __restrict__ nb) {
  const int wave = threadIdx.x >> 6, lane = threadIdx.x & 63;
  const long long row = (long long)blockIdx.x * 4 + wave;   // 16384 rows
  float2 v = ((const float2*)(x + row * DD))[lane];
  const double d0 = v.x, d1 = v.y;
  double s = d0 * d0 + d1 * d1;
  #pragma unroll
  for (int m = 32; m >= 1; m >>= 1) s += __shfl_xor(s, m, 64);
  double den = sqrt(s); den = den > 1e-12 ? den : 1e-12;
  if (lane == 0) rinv[row] = 1.0 / den;
  double2 o; o.x = d0 / den; o.y = d1 / den;
  nb[row * (DD / 2) + lane] = bf16rne((float)o.x) | (bf16rne((float)o.y) << 16);
}

// ---------------- fp32 top-8 machinery: branch-free sort + merge ----------------
#define CXF(i, j) { const float a_ = L[i], b_ = L[j]; L[i] = fmaxf(a_, b_); L[j] = fminf(a_, b_); }
// Batcher odd-even merge sort, 8 floats desc, 19 CEX, branch-free (network validated R12-as-u32)
__device__ __forceinline__ void sort8f(float (&L)[8]) {
  CXF(0, 1) CXF(2, 3) CXF(4, 5) CXF(6, 7)
  CXF(0, 2) CXF(1, 3) CXF(4, 6) CXF(5, 7)
  CXF(1, 2) CXF(5, 6)
  CXF(0, 4) CXF(1, 5) CXF(2, 6) CXF(3, 7)
  CXF(2, 4) CXF(3, 5)
  CXF(1, 2) CXF(3, 4) CXF(5, 6)
}
__device__ __forceinline__ void merge8f(float (&kv)[8], const float (&ov)[8]) {
  float L[8];
  #pragma unroll
  for (int i = 0; i < 8; ++i) L[i] = fmaxf(kv[i], ov[7 - i]);
  CXF(0, 4) CXF(1, 5) CXF(2, 6) CXF(3, 7)
  CXF(0, 2) CXF(1, 3) CXF(4, 6) CXF(5, 7)
  CXF(0, 1) CXF(2, 3) CXF(4, 5) CXF(6, 7)
  #pragma unroll
  for (int i = 0; i < 8; ++i) kv[i] = L[i];
}

// ---------------- u64 exact-key machinery (validated R5-R17) ----------------
__device__ __forceinline__ u64 make_key(double s, int col) {
  u64 u = (u64)__double_as_longlong(s);
  const u64 m = (u64)((long long)u >> 63);
  u ^= (m | 0x8000000000000000ull);
  return (u & ~2047ull) | (u64)(2047 - col);
}
__device__ __forceinline__ u64 umax64(u64 a, u64 b) { return a > b ? a : b; }
__device__ __forceinline__ u64 umin64(u64 a, u64 b) { return a > b ? b : a; }
__device__ __forceinline__ void merge8(u64 (&kv)[8], const u64 (&ov)[8]) {
  u64 L[8];
  #pragma unroll
  for (int i = 0; i < 8; ++i) L[i] = umax64(kv[i], ov[7 - i]);
#define CX(i, j) { const u64 a_ = L[i], b_ = L[j]; L[i] = umax64(a_, b_); L[j] = umin64(a_, b_); }
  CX(0, 4) CX(1, 5) CX(2, 6) CX(3, 7)
  CX(0, 2) CX(1, 3) CX(4, 6) CX(5, 7)
  CX(0, 1) CX(2, 3) CX(4, 5) CX(6, 7)
#undef CX
  #pragma unroll
  for (int i = 0; i < 8; ++i) kv[i] = L[i];
}
__device__ __forceinline__ void insert8u(u64 (&v)[8], u64 nk) {
  if (nk > v[7]) {
    v[7] = nk;
    #pragma unroll
    for (int q = 7; q >= 1; --q) {
      const u64 a = v[q - 1], b = v[q];
      const bool sw = b > a;
      v[q - 1] = sw ? b : a; v[q] = sw ? a : b;
    }
  }
}

// ---------------- k_gram: bf16 Gram once, stream bf16 scores (validated R17) ----------------
__global__ __launch_bounds__(256) void k_gram(const u32* __restrict__ nb,
                                              u16* __restrict__ scores) {
  const int tid = threadIdx.x; const int w = tid >> 6; const int l = tid & 63;
  const int q = l >> 4; const int m = l & 15;
  bf16x8 pvals = {0,0,0,0,0,0,0,0}, pones = {0,0,0,0,0,0,0,0};
  if (q == 0) {
    pvals[0] = (short)(__float_as_uint((float)(m + 1)) >> 16);
    pones[0] = (short)(__float_as_uint(1.0f) >> 16);
  }
  const f32x4 z4 = {0.0f, 0.0f, 0.0f, 0.0f};
  const f32x4 pr  = __builtin_amdgcn_mfma_f32_16x16x32_bf16(pvals, pones, z4, 0, 0, 0);
  const f32x4 pr2 = __builtin_amdgcn_mfma_f32_16x16x32_bf16(pones, pvals, z4, 0, 0, 0);
  int cof[4];
  #pragma unroll
  for (int p = 0; p < 4; ++p) cof[p] = (int)pr[p] - 1;
  const int rof = (int)pr2[0] - 1;
  const bool contig = (cof[1] == cof[0] + 1) && (cof[2] == cof[0] + 2) &&
                      (cof[3] == cof[0] + 3) && ((cof[0] & 3) == 0);
  const int rowblk = blockIdx.x >> 2; const int split = blockIdx.x & 3;
  const int row0 = rowblk * 64 + 16 * w;
  const int b = rowblk >> 5; const int c0 = split * 512;
  const u32* Bb = nb + ((long long)b * NN + c0) * (DD / 2);
  bf16x8 ar[4];
  { const u32* Ap = nb + (long long)(row0 + m) * (DD / 2) + 4 * q;
    #pragma unroll
    for (int cc = 0; cc < 4; ++cc) ar[cc] = *(const bf16x8*)(Ap + 16 * cc); }
  bf16x8 bcA[4], bcB[4];
  u16* rowbase = scores + (long long)(row0 + rof) * NN + c0;

#define LOADB(DST, T) { const u32* p_ = Bb + (long long)(16 * (T) + m) * (DD / 2) + 4 * q; \
  _Pragma("unroll") for (int cc = 0; cc < 4; ++cc) DST[cc] = *(const bf16x8*)(p_ + 16 * cc); }
#define GEMM16(ACC, BC) { ACC = z4;                                                \
  _Pragma("unroll") for (int cc = 0; cc < 4; ++cc)                                 \
    ACC = __builtin_amdgcn_mfma_f32_16x16x32_bf16(BC[cc], ar[cc], ACC, 0, 0, 0); }
#define STORE4(ACC, T) { u16* sp = rowbase + 16 * (T);                             \
    if (contig) {                                                                  \
      uint2 sv;                                                                    \
      sv.x = bf16rne(ACC[0]) | (bf16rne(ACC[1]) << 16);                            \
      sv.y = bf16rne(ACC[2]) | (bf16rne(ACC[3]) << 16);                            \
      *(uint2*)(sp + cof[0]) = sv;                                                 \
    } else {                                                                       \
      sp[cof[0]] = (u16)bf16rne(ACC[0]); sp[cof[1]] = (u16)bf16rne(ACC[1]);        \
      sp[cof[2]] = (u16)bf16rne(ACC[2]); sp[cof[3]] = (u16)bf16rne(ACC[3]);        \
    } }

  LOADB(bcA, 0)
  for (int t = 0; t < 32; t += 2) {
    LOADB(bcB, t + 1)
    { f32x4 acc; GEMM16(acc, bcA) STORE4(acc, t) }
    if (t + 2 < 32) LOADB(bcA, t + 2)
    { f32x4 acc; GEMM16(acc, bcB) STORE4(acc, t + 1) }
  }
#undef LOADB
#undef GEMM16
#undef STORE4
}

// ---------------- k_topk_exact: fused theta + survivors + fp64 rescore (R17 struct) ----------------
// R18: branch-free fold (4x sort8f+merge8f) replaces divergent insert8f chains.
__global__ __launch_bounds__(256) void k_topk_exact(const u16* __restrict__ scores,
                                                    const float* __restrict__ x,
                                                    const double* __restrict__ rinv,
                                                    float* __restrict__ out) {
  __shared__ u32 scnt[4];
  __shared__ u32 scand[4][CAP];

  const int w = threadIdx.x >> 6, l = threadIdx.x & 63;
  const int r = blockIdx.x * 4 + w;            // 0..16383
  const int n = r & (NN - 1);
  const long long brow = r - n;                // b*NN

  if (l == 0) scnt[w] = 0u;                    // wave-local; LDS in-order, no barrier

  // load the row's 2048 bf16 scores: 4 x uint4 = 32 scores/lane, coalesced
  const u32* row32 = (const u32*)(scores + (long long)r * NN);
  uint4 rv[4];
  #pragma unroll
  for (int i = 0; i < 4; ++i) rv[i] = ((const uint4*)row32)[i * 64 + l];

  float fs[32];
  #pragma unroll
  for (int i = 0; i < 4; ++i)
    #pragma unroll
    for (int c = 0; c < 4; ++c) {
      const u32 u = (&rv[i].x)[c];
      fs[i * 8 + 2 * c]     = __uint_as_float(u << 16);
      fs[i * 8 + 2 * c + 1] = __uint_as_float(u & 0xFFFF0000u);
    }

  // branch-free fold: 4 groups of 8 -> sort8f + merge8f into running top-8
  float kv8[8];
  {
    float L[8];
    #pragma unroll
    for (int s = 0; s < 8; ++s) L[s] = fs[s];
    sort8f(L);
    #pragma unroll
    for (int s = 0; s < 8; ++s) kv8[s] = L[s];
    #pragma unroll
    for (int g = 1; g < 4; ++g) {
      float M[8];
      #pragma unroll
      for (int s = 0; s < 8; ++s) M[s] = fs[g * 8 + s];
      sort8f(M);
      merge8f(kv8, M);
    }
  }
  // butterfly: all lanes converge to the row's top-8 values
  #pragma unroll
  for (int mk = 1; mk <= 32; mk <<= 1) {
    float ov[8];
    #pragma unroll
    for (int s = 0; s < 8; ++s) ov[s] = __shfl_xor(kv8[s], mk, 64);
    merge8f(kv8, ov);
  }
  const float th = kv8[7] - MARGIN;

  // push survivors into the wave's LDS buffer (~10/row expected)
  #pragma unroll
  for (int i = 0; i < 4; ++i)
    #pragma unroll
    for (int c = 0; c < 4; ++c) {
      const int colb = 8 * (i * 64 + l) + 2 * c;
      if (fs[i * 8 + 2 * c] >= th) {
        const u32 idx = atomicAdd(&scnt[w], 1u);
        if (idx < CAP) scand[w][idx] = (u32)colb;
      }
      if (fs[i * 8 + 2 * c + 1] >= th) {
        const u32 idx = atomicAdd(&scnt[w], 1u);
        if (idx < CAP) scand[w][idx] = (u32)(colb + 1);
      }
    }

  const int c = (int)scnt[w];                  // wave-lockstep: all pushes complete
  const float2 a2 = ((const float2*)(x + (long long)r * DD))[l];
  const double ri = rinv[r];
  u64 kv[8];
  #pragma unroll
  for (int s = 0; s < 8; ++s) kv[s] = 0ull;

  if (c <= CAP) {
    for (int i = 0; i < c; i += 4) {
      float2 vv[4]; int col[4];
      #pragma unroll
      for (int g = 0; g < 4; ++g) {
        const int idx = i + g;
        col[g] = (idx < c) ? ((int)scand[w][idx] & (NN - 1)) : 0;
        vv[g] = ((const float2*)(x + (brow + col[g]) * DD))[l];
      }
      #pragma unroll
      for (int g = 0; g < 4; ++g) {
        double d = fma((double)a2.x, (double)vv[g].x, (double)a2.y * (double)vv[g].y);
        #pragma unroll
        for (int mk = 1; mk <= 32; mk <<= 1) d += __shfl_xor(d, mk, 64);
        if (i + g < c) insert8u(kv, make_key(d * ri * rinv[brow + col[g]], col[g]));
      }
    }
  } else {
    // overflow fallback (never expected): full exact row scan (validated)
    for (int base = 0; base < NN; base += 64) {
      const int col = base + l;
      const float* ap = x + (long long)r * DD;
      const float* cp = x + (brow + col) * DD;
      double d = 0.0;
      for (int kk = 0; kk < 64; ++kk) {
        const float2 av = ((const float2*)ap)[kk];
        const float2 bv = ((const float2*)cp)[kk];
        d = fma((double)av.x, (double)bv.x, fma((double)av.y, (double)bv.y, d));
      }
      d = d * ri * rinv[brow + col];
      u64 one[8];
      one[0] = make_key(d, col);
      #pragma unroll
      for (int s = 1; s < 8; ++s) one[s] = 0ull;
      #pragma unroll
      for (int mk = 1; mk <= 32; mk <<= 1) {
        u64 ov[8];
        #pragma unroll
        for (int s = 0; s < 8; ++s) ov[s] = __shfl_xor(one[s], mk, 64);
        merge8(one, ov);
      }
      merge8(kv, one);
    }
  }

  const long long orow = (long long)r * NN;
  const long long obase = brow * NN;           // b*NN*NN
  if (l == 8) out[orow + n] = 1.0f;            // self loop
  #pragma unroll
  for (int s = 0; s < 8; ++s) {
    const int mcol = 2047 - (int)(kv[s] & 2047ull);
    if (l == s) {
      out[orow + mcol] = 1.0f;
      out[obase + (long long)mcol * NN + n] = 1.0f;
    }
  }
}

extern "C" void kernel_launch(void* const* d_in, const int* in_sizes, int n_in,
                              void* d_out, int out_size, void* d_ws, size_t ws_size,
                              hipStream_t stream) {
  const float* x = (const float*)d_in[0];
  float* out = (float*)d_out;
  char* ws = (char*)d_ws;
  u32* nb = (u32*)ws;                                //  4,194,304 B (bf16 normed)
  double* rinv = (double*)(ws + 4194304);            //    131,072 B
  u16* scores = (u16*)(ws + 4325376);                // 67,108,864 B (bf16 scores)

  hipMemsetAsync(d_out, 0, (size_t)out_size * sizeof(float), stream);
  hipLaunchKernelGGL(k_normalize, dim3(NROWS / 4), dim3(256), 0, stream, x, rinv, nb);
  hipLaunchKernelGGL(k_gram, dim3(1024), dim3(256), 0, stream, nb, scores);
  hipLaunchKernelGGL(k_topk_exact, dim3(NROWS / 4), dim3(256), 0, stream, scores, x, rinv, out);
}